// Round 1
// baseline (655.661 us; speedup 1.0000x reference)
//
#include <hip/hip_runtime.h>
#include <hip/hip_bf16.h>

// GQA flash attention fwd, causal + sliding window 1024.
// B=2, S=2048, Hq=32, Hkv=8 (group 4), D=128.
// FP32 in/out; bf16 MFMA compute, fp32 accumulate. No +-INFINITY anywhere.
//
// This round: kill the 1.145e8 LDS bank conflicts. The V-transpose scalar
// stores put all 64 lanes on 2 banks (32-way). V now stays row-major in a
// [d-block][key][16] subtiled layout (conflict-free 8B stores) and the PV
// B-fragments are read with ds_read_b64_tr_b16 (hardware 4x16 transpose).
// P likewise: P^T stored with conflict-free 8B quad stores, A-fragments via
// tr reads. Inline-asm ds_read + counted lgkmcnt + sched_barrier(0) per the
// compiler-hoisting errata.

#define H_Q 32
#define H_KV 8
#define HDIM 128
#define SEQLEN 2048
#define NBATCH 2
#define WIN 1024
#define QK_SCALE 0.08838834764831845f
#define LOG2E 1.4426950408889634f
#define SCALE_LOG2E (QK_SCALE * LOG2E)

#define NEG_BIG  (-3.0e38f)   // finite "masked" sentinel
#define NEG_CLMP (-1.0e30f)   // exponent-reference clamp: exp2(NEG_BIG-NEG_CLMP)==0

#define QPITCH (H_Q * HDIM)   // 4096 floats
#define KPITCH (H_KV * HDIM)  // 1024 floats

typedef __attribute__((ext_vector_type(8))) short  short8;   // 8 bf16 = 4 VGPR
typedef __attribute__((ext_vector_type(4))) short  short4v;  // 4 bf16 = 8 B
typedef __attribute__((ext_vector_type(4))) float  floatx4;

static __device__ __forceinline__ short bf16bits(float x) {
    return __builtin_bit_cast(short, __float2bfloat16(x));
}

// Hardware transpose read: each 16-lane group addresses a contiguous 128B
// region (lane addr = region_base + ln16*8); lane ln16 receives column ln16
// of that region viewed as a 4x16 row-major bf16 tile (elem j = row j).
#define TR_READ(dst, addr, OFFSTR) \
    asm volatile("ds_read_b64_tr_b16 %0, %1 offset:" OFFSTR : "=v"(dst) : "v"(addr))

#define CAT8(a, b) __builtin_shufflevector(a, b, 0, 1, 2, 3, 4, 5, 6, 7)

__global__ __launch_bounds__(256, 3)
void fa_fwd(const float* __restrict__ Q,
            const float* __restrict__ K,
            const float* __restrict__ V,
            float* __restrict__ O)
{
    __shared__ __align__(16) short lds_k[64][136];    // K tile [key][d] (bf16), padded pitch
    __shared__ __align__(16) short lds_v[8][64][16];  // V tile [d>>4][key][d&15] (row-major subtiled)
    __shared__ __align__(16) short lds_pt[4][64][16]; // per-wave P^T [key][q]

    const int bi  = blockIdx.x;
    const int qt  = bi & 31;          // 32 q-tiles of 64
    const int h   = (bi >> 5) & 31;
    const int b   = bi >> 10;
    const int kvh = h >> 2;           // GQA group of 4
    const int q0  = qt << 6;

    const int tid  = threadIdx.x;
    const int wid  = tid >> 6;        // wave id 0..3, owns rows q0+wid*16..+15
    const int lane = tid & 63;
    const int ln16 = lane & 15;
    const int lg   = lane >> 4;       // lane group 0..3

    const float* Qb = Q + (size_t)b * SEQLEN * QPITCH + (size_t)h * HDIM;
    const float* Kb = K + (size_t)b * SEQLEN * KPITCH + (size_t)kvh * HDIM;
    const float* Vb = V + (size_t)b * SEQLEN * KPITCH + (size_t)kvh * HDIM;
    float*       Ob = O + (size_t)b * SEQLEN * QPITCH + (size_t)h * HDIM;

    // LDS byte addresses for tr reads (AS3 offset = low 32 bits of generic ptr).
    const uint32_t v_base  = (uint32_t)(uintptr_t)&lds_v[0][0][0]
                           + (uint32_t)(lg * 256 + ln16 * 8);
    const uint32_t pt_base = (uint32_t)(uintptr_t)&lds_pt[wid][0][0]
                           + (uint32_t)(lg * 256 + ln16 * 8);

    // ---- Q fragments (A operand), held in registers for the whole kernel.
    // A layout: m = ln16 (query row), k = lg*8 + j within each 32-wide k-step.
    short8 qf[4];
    {
        const int qrow = q0 + wid * 16 + ln16;
        const float* qs = Qb + (size_t)qrow * QPITCH + lg * 8;
        #pragma unroll
        for (int kk = 0; kk < 4; ++kk) {
            floatx4 a = *(const floatx4*)(qs + kk * 32);
            floatx4 c = *(const floatx4*)(qs + kk * 32 + 4);
            short8 f;
            #pragma unroll
            for (int j = 0; j < 4; ++j) { f[j] = bf16bits(a[j]); f[4 + j] = bf16bits(c[j]); }
            qf[kk] = f;
        }
    }

    floatx4 oacc[8];                  // O accum, C layout: col=d (ln16), row=lg*4+r
    #pragma unroll
    for (int i = 0; i < 8; ++i) oacc[i] = (floatx4){0.f, 0.f, 0.f, 0.f};
    float m_r[4], l_r[4];             // online-softmax state for rows lg*4+r
    #pragma unroll
    for (int r = 0; r < 4; ++r) { m_r[r] = NEG_BIG; l_r[r] = 0.f; }

    int kvlo = q0 - (WIN - 1);
    if (kvlo < 0) kvlo = 0;
    kvlo &= ~63;

    for (int kk0 = kvlo; kk0 <= q0; kk0 += 64) {
        __syncthreads();              // previous tile's LDS reads done
        // ---- stage K [64][128] and V (row-major subtiled) into LDS as bf16.
        // flat float4 index fi = i*256 + tid: lane-consecutive addresses.
        #pragma unroll
        for (int i = 0; i < 8; ++i) {
            const int fi  = i * 256 + tid;     // 0..2047
            const int key = fi >> 5;           // 0..63
            const int c4  = (fi & 31) * 4;     // float col 0,4,...,124
            const size_t grow = (size_t)(kk0 + key) * KPITCH + c4;
            floatx4 kv = *(const floatx4*)(Kb + grow);
            short4v ksv;
            #pragma unroll
            for (int j = 0; j < 4; ++j) ksv[j] = bf16bits(kv[j]);
            *(short4v*)&lds_k[key][c4] = ksv;
            floatx4 vv = *(const floatx4*)(Vb + grow);
            short4v vsv;
            #pragma unroll
            for (int j = 0; j < 4; ++j) vsv[j] = bf16bits(vv[j]);
            *(short4v*)&lds_v[c4 >> 4][key][c4 & 15] = vsv;   // 8B, conflict-free
        }
        __syncthreads();

        // ---- S = Q K^T  (16 MFMAs per wave)
        float sc[4][4];
        #pragma unroll
        for (int nt = 0; nt < 4; ++nt) {
            floatx4 acc = (floatx4){0.f, 0.f, 0.f, 0.f};
            #pragma unroll
            for (int kk = 0; kk < 4; ++kk) {
                short8 kf = *(const short8*)&lds_k[nt * 16 + ln16][kk * 32 + lg * 8];
                acc = __builtin_amdgcn_mfma_f32_16x16x32_bf16(qf[kk], kf, acc, 0, 0, 0);
            }
            #pragma unroll
            for (int r = 0; r < 4; ++r) sc[nt][r] = acc[r];
        }

        // ---- scale + mask (interior tiles skip the mask ALU entirely)
        const bool full = (kk0 + 63 <= q0) && (kk0 >= q0 - 960);
        float pm[4];
        #pragma unroll
        for (int r = 0; r < 4; ++r) pm[r] = NEG_BIG;
        if (full) {
            #pragma unroll
            for (int nt = 0; nt < 4; ++nt)
                #pragma unroll
                for (int r = 0; r < 4; ++r) {
                    sc[nt][r] *= SCALE_LOG2E;
                    pm[r] = fmaxf(pm[r], sc[nt][r]);
                }
        } else {
            #pragma unroll
            for (int nt = 0; nt < 4; ++nt) {
                const int kcol = kk0 + nt * 16 + ln16;
                #pragma unroll
                for (int r = 0; r < 4; ++r) {
                    const int qrow = q0 + wid * 16 + lg * 4 + r;
                    const bool ok = (kcol <= qrow) && (qrow - kcol < WIN);
                    sc[nt][r] = ok ? sc[nt][r] * SCALE_LOG2E : NEG_BIG;
                    pm[r] = fmaxf(pm[r], sc[nt][r]);
                }
            }
        }
        // row-reduce max across the 16 lanes holding each row
        #pragma unroll
        for (int r = 0; r < 4; ++r)
            #pragma unroll
            for (int off = 1; off < 16; off <<= 1)
                pm[r] = fmaxf(pm[r], __shfl_xor(pm[r], off, 16));

        float alpha[4], mne[4];
        #pragma unroll
        for (int r = 0; r < 4; ++r) {
            const float mn = fmaxf(m_r[r], pm[r]);        // finite always
            const float me = fmaxf(mn, NEG_CLMP);         // exponent reference
            alpha[r] = exp2f(m_r[r] - me);                // NEG_BIG-NEG_CLMP -> 0
            m_r[r] = mn;
            mne[r] = me;
        }

        // ---- P = exp2(s - m), write P^T [key][q] as conflict-free 8B quads
        float psum[4] = {0.f, 0.f, 0.f, 0.f};
        #pragma unroll
        for (int nt = 0; nt < 4; ++nt) {
            short4v pq;
            #pragma unroll
            for (int r = 0; r < 4; ++r) {
                const float p = exp2f(sc[nt][r] - mne[r]);  // masked -> exact 0
                psum[r] += p;
                pq[r] = bf16bits(p);
            }
            *(short4v*)&lds_pt[wid][nt * 16 + ln16][lg * 4] = pq;
        }
        #pragma unroll
        for (int r = 0; r < 4; ++r) {
            #pragma unroll
            for (int off = 1; off < 16; off <<= 1)
                psum[r] += __shfl_xor(psum[r], off, 16);
            l_r[r] = l_r[r] * alpha[r] + psum[r];
        }
        #pragma unroll
        for (int dt = 0; dt < 8; ++dt)
            #pragma unroll
            for (int r = 0; r < 4; ++r) oacc[dt][r] *= alpha[r];

        // Fence: orders the compiler's P^T ds_writes before our asm tr reads
        // (and protects lds_v against the next iteration's overwrite).
        __syncthreads();

        // ---- O += P V  via hardware-transpose reads (16 MFMAs per wave)
        // A-frag (P): lane m=ln16 (q-row), k = ks*32+lg*8+j  -> P^T[k][ln16]
        // B-frag (V): lane n=ln16 (d-col), k = ks*32+lg*8+j  -> V[k][dt*16+ln16]
        #pragma unroll
        for (int ks = 0; ks < 2; ++ks) {
            const uint32_t pa = pt_base + (uint32_t)(ks * 1024);
            const uint32_t va = v_base  + (uint32_t)(ks * 1024);
            short4v p0, p1;
            short4v w00, w01, w10, w11, w20, w21, w30, w31;
            short4v w40, w41, w50, w51, w60, w61, w70, w71;
            TR_READ(p0,  pa, "0");     TR_READ(p1,  pa, "128");
            TR_READ(w00, va, "0");     TR_READ(w01, va, "128");
            TR_READ(w10, va, "2048");  TR_READ(w11, va, "2176");
            TR_READ(w20, va, "4096");  TR_READ(w21, va, "4224");
            TR_READ(w30, va, "6144");  TR_READ(w31, va, "6272");
            TR_READ(w40, va, "8192");  TR_READ(w41, va, "8320");
            TR_READ(w50, va, "10240"); TR_READ(w51, va, "10368");
            TR_READ(w60, va, "12288"); TR_READ(w61, va, "12416");
            TR_READ(w70, va, "14336"); TR_READ(w71, va, "14464");
            // first 12 reads (p + dt 0..3) done when <=8 outstanding
            asm volatile("s_waitcnt lgkmcnt(8)");
            __builtin_amdgcn_sched_barrier(0);
            const short8 pf = CAT8(p0, p1);
            oacc[0] = __builtin_amdgcn_mfma_f32_16x16x32_bf16(pf, CAT8(w00, w01), oacc[0], 0, 0, 0);
            oacc[1] = __builtin_amdgcn_mfma_f32_16x16x32_bf16(pf, CAT8(w10, w11), oacc[1], 0, 0, 0);
            oacc[2] = __builtin_amdgcn_mfma_f32_16x16x32_bf16(pf, CAT8(w20, w21), oacc[2], 0, 0, 0);
            oacc[3] = __builtin_amdgcn_mfma_f32_16x16x32_bf16(pf, CAT8(w30, w31), oacc[3], 0, 0, 0);
            asm volatile("s_waitcnt lgkmcnt(0)");
            __builtin_amdgcn_sched_barrier(0);
            oacc[4] = __builtin_amdgcn_mfma_f32_16x16x32_bf16(pf, CAT8(w40, w41), oacc[4], 0, 0, 0);
            oacc[5] = __builtin_amdgcn_mfma_f32_16x16x32_bf16(pf, CAT8(w50, w51), oacc[5], 0, 0, 0);
            oacc[6] = __builtin_amdgcn_mfma_f32_16x16x32_bf16(pf, CAT8(w60, w61), oacc[6], 0, 0, 0);
            oacc[7] = __builtin_amdgcn_mfma_f32_16x16x32_bf16(pf, CAT8(w70, w71), oacc[7], 0, 0, 0);
        }
    }

    // ---- epilogue: normalize and store fp32
    #pragma unroll
    for (int r = 0; r < 4; ++r) {
        const float inv = 1.0f / l_r[r];   // diagonal key always valid -> l_r>0
        const int qrow = q0 + wid * 16 + lg * 4 + r;
        float* dst = Ob + (size_t)qrow * QPITCH;
        #pragma unroll
        for (int dt = 0; dt < 8; ++dt)
            dst[dt * 16 + ln16] = oacc[dt][r] * inv;
    }
}

extern "C" void kernel_launch(void* const* d_in, const int* in_sizes, int n_in,
                              void* d_out, int out_size, void* d_ws, size_t ws_size,
                              hipStream_t stream) {
    const float* Q = (const float*)d_in[0];
    const float* K = (const float*)d_in[1];
    const float* V = (const float*)d_in[2];
    float* O = (float*)d_out;
    dim3 grid(NBATCH * H_Q * (SEQLEN / 64));   // 2048 blocks: (b, h, qtile)
    fa_fwd<<<grid, 256, 0, stream>>>(Q, K, V, O);
}

// Round 2
// 341.166 us; speedup vs baseline: 1.9218x; 1.9218x over previous
//
#include <hip/hip_runtime.h>
#include <hip/hip_bf16.h>

// GQA flash attention fwd, causal + sliding window 1024.
// B=2, S=2048, Hq=32, Hkv=8 (group 4), D=128.
// FP32 in/out; bf16 MFMA compute, fp32 accumulate. No +-INFINITY anywhere.
//
// Round 2: the kernel is latency-bound (~11k cycles/tile vs ~2.5k of work);
// staging was load->convert->store serialized between barriers every tile.
// Now the NEXT tile's 16 float4 global loads are issued right after the
// current tile is staged (T14 async-STAGE split) so HBM latency hides under
// QK+softmax+PV. PV tr-read block split into two small chunks (<=10 live
// asm temps) to kill the round-1 scratch spills; barrier #3 replaced by a
// wave-local lgkmcnt(0) fence (P^T is wave-private).

#define H_Q 32
#define H_KV 8
#define HDIM 128
#define SEQLEN 2048
#define NBATCH 2
#define WIN 1024
#define QK_SCALE 0.08838834764831845f
#define LOG2E 1.4426950408889634f
#define SCALE_LOG2E (QK_SCALE * LOG2E)

#define NEG_BIG  (-3.0e38f)   // finite "masked" sentinel
#define NEG_CLMP (-1.0e30f)   // exponent-reference clamp: exp2(NEG_BIG-NEG_CLMP)==0

#define QPITCH (H_Q * HDIM)   // 4096 floats
#define KPITCH (H_KV * HDIM)  // 1024 floats

typedef __attribute__((ext_vector_type(8))) short  short8;   // 8 bf16 = 4 VGPR
typedef __attribute__((ext_vector_type(4))) short  short4v;  // 4 bf16 = 8 B
typedef __attribute__((ext_vector_type(4))) float  floatx4;

static __device__ __forceinline__ short bf16bits(float x) {
    return __builtin_bit_cast(short, __float2bfloat16(x));
}

// Hardware transpose read: each 16-lane group addresses a contiguous 128B
// region (lane addr = region_base + ln16*8); lane ln16 receives column ln16
// of that region viewed as a 4x16 row-major bf16 tile (elem j = row j).
#define TR_READ(dst, addr, OFFSTR) \
    asm volatile("ds_read_b64_tr_b16 %0, %1 offset:" OFFSTR : "=v"(dst) : "v"(addr))

#define CAT8(a, b) __builtin_shufflevector(a, b, 0, 1, 2, 3, 4, 5, 6, 7)

#define MFMA_BF16 __builtin_amdgcn_mfma_f32_16x16x32_bf16

__global__ __launch_bounds__(256, 2)
void fa_fwd(const float* __restrict__ Q,
            const float* __restrict__ K,
            const float* __restrict__ V,
            float* __restrict__ O)
{
    __shared__ __align__(16) short lds_k[64][136];    // K tile [key][d] (bf16), padded pitch
    __shared__ __align__(16) short lds_v[8][64][16];  // V tile [d>>4][key][d&15] subtiled
    __shared__ __align__(16) short lds_pt[4][64][16]; // per-wave P^T [key][q]

    const int bi  = blockIdx.x;
    const int qt  = bi & 31;          // 32 q-tiles of 64
    const int h   = (bi >> 5) & 31;
    const int b   = bi >> 10;
    const int kvh = h >> 2;           // GQA group of 4
    const int q0  = qt << 6;

    const int tid  = threadIdx.x;
    const int wid  = tid >> 6;        // wave id 0..3, owns rows q0+wid*16..+15
    const int lane = tid & 63;
    const int ln16 = lane & 15;
    const int lg   = lane >> 4;       // lane group 0..3

    const float* Qb = Q + (size_t)b * SEQLEN * QPITCH + (size_t)h * HDIM;
    const float* Kb = K + (size_t)b * SEQLEN * KPITCH + (size_t)kvh * HDIM;
    const float* Vb = V + (size_t)b * SEQLEN * KPITCH + (size_t)kvh * HDIM;
    float*       Ob = O + (size_t)b * SEQLEN * QPITCH + (size_t)h * HDIM;

    // LDS byte addresses for tr reads.
    const uint32_t v_base  = (uint32_t)(uintptr_t)&lds_v[0][0][0]
                           + (uint32_t)(lg * 256 + ln16 * 8);
    const uint32_t pt_base = (uint32_t)(uintptr_t)&lds_pt[wid][0][0]
                           + (uint32_t)(lg * 256 + ln16 * 8);

    int kvlo = q0 - (WIN - 1);
    if (kvlo < 0) kvlo = 0;
    kvlo &= ~63;

    // ---- K/V register prefetch (T14): 16 float4 in flight across compute.
    floatx4 pk[8], pv[8];
    auto issue_kv = [&](int kt) {
        #pragma unroll
        for (int i = 0; i < 8; ++i) {
            const int fi  = i * 256 + tid;     // 0..2047
            const int key = fi >> 5;           // 0..63
            const int c4  = (fi & 31) * 4;     // float col 0,4,...,124
            const size_t grow = (size_t)(kt + key) * KPITCH + c4;
            pk[i] = *(const floatx4*)(Kb + grow);
            pv[i] = *(const floatx4*)(Vb + grow);
        }
    };
    issue_kv(kvlo);   // first tile's loads fly while we set up Q

    // ---- Q fragments (A operand), held in registers for the whole kernel.
    // A layout: m = ln16 (query row), k = lg*8 + j within each 32-wide k-step.
    short8 qf[4];
    {
        const int qrow = q0 + wid * 16 + ln16;
        const float* qs = Qb + (size_t)qrow * QPITCH + lg * 8;
        #pragma unroll
        for (int kk = 0; kk < 4; ++kk) {
            floatx4 a = *(const floatx4*)(qs + kk * 32);
            floatx4 c = *(const floatx4*)(qs + kk * 32 + 4);
            short8 f;
            #pragma unroll
            for (int j = 0; j < 4; ++j) { f[j] = bf16bits(a[j]); f[4 + j] = bf16bits(c[j]); }
            qf[kk] = f;
        }
    }

    floatx4 oacc[8];                  // O accum, C layout: col=d (ln16), row=lg*4+r
    #pragma unroll
    for (int i = 0; i < 8; ++i) oacc[i] = (floatx4){0.f, 0.f, 0.f, 0.f};
    float m_r[4], l_r[4];             // online-softmax state for rows lg*4+r
    #pragma unroll
    for (int r = 0; r < 4; ++r) { m_r[r] = NEG_BIG; l_r[r] = 0.f; }

    for (int kk0 = kvlo; kk0 <= q0; kk0 += 64) {
        __syncthreads();              // previous tile's LDS reads done
        // ---- convert the prefetched tile and store to LDS (bf16).
        #pragma unroll
        for (int i = 0; i < 8; ++i) {
            const int fi  = i * 256 + tid;
            const int key = fi >> 5;
            const int c4  = (fi & 31) * 4;
            short4v ksv, vsv;
            #pragma unroll
            for (int j = 0; j < 4; ++j) {
                ksv[j] = bf16bits(pk[i][j]);
                vsv[j] = bf16bits(pv[i][j]);
            }
            *(short4v*)&lds_k[key][c4] = ksv;                 // 8B, ~2-way: free
            *(short4v*)&lds_v[c4 >> 4][key][c4 & 15] = vsv;   // 8B, conflict-free
        }
        __syncthreads();

        // ---- issue next tile's loads NOW; latency hides under QK+softmax+PV.
        if (kk0 + 64 <= q0) issue_kv(kk0 + 64);

        // ---- S = Q K^T  (16 MFMAs per wave)
        float sc[4][4];
        #pragma unroll
        for (int nt = 0; nt < 4; ++nt) {
            floatx4 acc = (floatx4){0.f, 0.f, 0.f, 0.f};
            #pragma unroll
            for (int kk = 0; kk < 4; ++kk) {
                short8 kf = *(const short8*)&lds_k[nt * 16 + ln16][kk * 32 + lg * 8];
                acc = MFMA_BF16(qf[kk], kf, acc, 0, 0, 0);
            }
            #pragma unroll
            for (int r = 0; r < 4; ++r) sc[nt][r] = acc[r];
        }

        // ---- scale + mask (interior tiles skip the mask ALU entirely)
        const bool full = (kk0 + 63 <= q0) && (kk0 >= q0 - 960);
        float pm[4];
        #pragma unroll
        for (int r = 0; r < 4; ++r) pm[r] = NEG_BIG;
        if (full) {
            #pragma unroll
            for (int nt = 0; nt < 4; ++nt)
                #pragma unroll
                for (int r = 0; r < 4; ++r) {
                    sc[nt][r] *= SCALE_LOG2E;
                    pm[r] = fmaxf(pm[r], sc[nt][r]);
                }
        } else {
            #pragma unroll
            for (int nt = 0; nt < 4; ++nt) {
                const int kcol = kk0 + nt * 16 + ln16;
                #pragma unroll
                for (int r = 0; r < 4; ++r) {
                    const int qrow = q0 + wid * 16 + lg * 4 + r;
                    const bool ok = (kcol <= qrow) && (qrow - kcol < WIN);
                    sc[nt][r] = ok ? sc[nt][r] * SCALE_LOG2E : NEG_BIG;
                    pm[r] = fmaxf(pm[r], sc[nt][r]);
                }
            }
        }
        // row-reduce max across the 16 lanes holding each row
        #pragma unroll
        for (int r = 0; r < 4; ++r)
            #pragma unroll
            for (int off = 1; off < 16; off <<= 1)
                pm[r] = fmaxf(pm[r], __shfl_xor(pm[r], off, 16));

        float alpha[4], mne[4];
        #pragma unroll
        for (int r = 0; r < 4; ++r) {
            const float mn = fmaxf(m_r[r], pm[r]);        // finite always
            const float me = fmaxf(mn, NEG_CLMP);         // exponent reference
            alpha[r] = exp2f(m_r[r] - me);                // NEG_BIG-NEG_CLMP -> 0
            m_r[r] = mn;
            mne[r] = me;
        }

        // ---- P = exp2(s - m), write P^T [key][q] as conflict-free 8B quads
        float psum[4] = {0.f, 0.f, 0.f, 0.f};
        #pragma unroll
        for (int nt = 0; nt < 4; ++nt) {
            short4v pq;
            #pragma unroll
            for (int r = 0; r < 4; ++r) {
                const float p = exp2f(sc[nt][r] - mne[r]);  // masked -> exact 0
                psum[r] += p;
                pq[r] = bf16bits(p);
            }
            *(short4v*)&lds_pt[wid][nt * 16 + ln16][lg * 4] = pq;
        }
        #pragma unroll
        for (int r = 0; r < 4; ++r) {
            #pragma unroll
            for (int off = 1; off < 16; off <<= 1)
                psum[r] += __shfl_xor(psum[r], off, 16);
            l_r[r] = l_r[r] * alpha[r] + psum[r];
        }
        #pragma unroll
        for (int dt = 0; dt < 8; ++dt)
            #pragma unroll
            for (int r = 0; r < 4; ++r) oacc[dt][r] *= alpha[r];

        // Wave-local fence: P^T is read only by the wave that wrote it, so a
        // counted-to-zero LDS drain replaces the third __syncthreads.
        asm volatile("s_waitcnt lgkmcnt(0)" ::: "memory");
        __builtin_amdgcn_sched_barrier(0);

        // ---- O += P V  via hardware-transpose reads (16 MFMAs per wave),
        // two chunks per ks to keep <=10 asm temps live (no spills).
        #pragma unroll
        for (int ks = 0; ks < 2; ++ks) {
            const uint32_t pa = pt_base + (uint32_t)(ks * 1024);
            const uint32_t va = v_base  + (uint32_t)(ks * 1024);
            short4v p0, p1, w0a, w0b, w1a, w1b, w2a, w2b, w3a, w3b;
            TR_READ(p0,  pa, "0");     TR_READ(p1,  pa, "128");
            TR_READ(w0a, va, "0");     TR_READ(w0b, va, "128");
            TR_READ(w1a, va, "2048");  TR_READ(w1b, va, "2176");
            TR_READ(w2a, va, "4096");  TR_READ(w2b, va, "4224");
            TR_READ(w3a, va, "6144");  TR_READ(w3b, va, "6272");
            asm volatile("s_waitcnt lgkmcnt(0)" ::: "memory");
            __builtin_amdgcn_sched_barrier(0);
            const short8 pf = CAT8(p0, p1);
            oacc[0] = MFMA_BF16(pf, CAT8(w0a, w0b), oacc[0], 0, 0, 0);
            oacc[1] = MFMA_BF16(pf, CAT8(w1a, w1b), oacc[1], 0, 0, 0);
            oacc[2] = MFMA_BF16(pf, CAT8(w2a, w2b), oacc[2], 0, 0, 0);
            oacc[3] = MFMA_BF16(pf, CAT8(w3a, w3b), oacc[3], 0, 0, 0);
            short4v x0a, x0b, x1a, x1b, x2a, x2b, x3a, x3b;
            TR_READ(x0a, va, "8192");  TR_READ(x0b, va, "8320");
            TR_READ(x1a, va, "10240"); TR_READ(x1b, va, "10368");
            TR_READ(x2a, va, "12288"); TR_READ(x2b, va, "12416");
            TR_READ(x3a, va, "14336"); TR_READ(x3b, va, "14464");
            asm volatile("s_waitcnt lgkmcnt(0)" ::: "memory");
            __builtin_amdgcn_sched_barrier(0);
            oacc[4] = MFMA_BF16(pf, CAT8(x0a, x0b), oacc[4], 0, 0, 0);
            oacc[5] = MFMA_BF16(pf, CAT8(x1a, x1b), oacc[5], 0, 0, 0);
            oacc[6] = MFMA_BF16(pf, CAT8(x2a, x2b), oacc[6], 0, 0, 0);
            oacc[7] = MFMA_BF16(pf, CAT8(x3a, x3b), oacc[7], 0, 0, 0);
        }
    }

    // ---- epilogue: normalize and store fp32
    #pragma unroll
    for (int r = 0; r < 4; ++r) {
        const float inv = 1.0f / l_r[r];   // diagonal key always valid -> l_r>0
        const int qrow = q0 + wid * 16 + lg * 4 + r;
        float* dst = Ob + (size_t)qrow * QPITCH;
        #pragma unroll
        for (int dt = 0; dt < 8; ++dt)
            dst[dt * 16 + ln16] = oacc[dt][r] * inv;
    }
}

extern "C" void kernel_launch(void* const* d_in, const int* in_sizes, int n_in,
                              void* d_out, int out_size, void* d_ws, size_t ws_size,
                              hipStream_t stream) {
    const float* Q = (const float*)d_in[0];
    const float* K = (const float*)d_in[1];
    const float* V = (const float*)d_in[2];
    float* O = (float*)d_out;
    dim3 grid(NBATCH * H_Q * (SEQLEN / 64));   // 2048 blocks: (b, h, qtile)
    fa_fwd<<<grid, 256, 0, stream>>>(Q, K, V, O);
}

// Round 4
// 292.080 us; speedup vs baseline: 2.2448x; 1.1681x over previous
//
#include <hip/hip_runtime.h>
#include <hip/hip_bf16.h>

// GQA flash attention fwd, causal + sliding window 1024.
// B=2, S=2048, Hq=32, Hkv=8 (group 4), D=128.
// FP32 in/out; bf16 MFMA compute, fp32 accumulate. No +-INFINITY anywhere.
//
// Round 4 = round 3 with the cvt_kv grid fixed (was 2x oversized -> OOB
// reads/writes -> abort; each thread handles K AND V, so threads needed are
// WS_ELEMS/4, i.e. 4096 blocks, not 8192). Index guard added.
//
// Structure (unchanged):
//  - Pre-pass converts K,V -> bf16 ONCE into d_ws, pre-laid-out:
//      ws_K: per 64-key tile, rows [key][d] with element-XOR swizzle
//            (d ^ ((key&7)<<3)) so a LINEAR copy into LDS gives the
//            bank-spread layout (global_load_lds can't scatter).
//      ws_V: per tile, subtiled [d>>4][key][d&15] (tr-read layout), linear.
//  - Main kernel stages via global_load_lds dwordx4 (no VGPR roundtrip, no
//    converts), raw s_barrier + counted vmcnt(4) (never 0 mid-loop).
//  - LDS = 40960 B exactly, 4 blocks/CU target.
//  - Long q-tiles first + XCD-chunked block swizzle.
//  - Fallback to the verified round-2 kernel if ws_size < 16 MiB.

#define H_Q 32
#define H_KV 8
#define HDIM 128
#define SEQLEN 2048
#define NBATCH 2
#define WIN 1024
#define QK_SCALE 0.08838834764831845f
#define LOG2E 1.4426950408889634f
#define SCALE_LOG2E (QK_SCALE * LOG2E)

#define NEG_BIG  (-3.0e38f)
#define NEG_CLMP (-1.0e30f)

#define QPITCH (H_Q * HDIM)   // 4096 floats
#define KPITCH (H_KV * HDIM)  // 1024 floats

#define WS_ELEMS ((size_t)NBATCH * H_KV * SEQLEN * HDIM)   // 4,194,304 shorts
#define WS_BYTES (2 * WS_ELEMS * sizeof(short))            // 16,777,216

typedef __attribute__((ext_vector_type(8))) short  short8;
typedef __attribute__((ext_vector_type(4))) short  short4v;
typedef __attribute__((ext_vector_type(4))) float  floatx4;

static __device__ __forceinline__ short bf16bits(float x) {
    return __builtin_bit_cast(short, __float2bfloat16(x));
}

#define TR_READ(dst, addr, OFFSTR) \
    asm volatile("ds_read_b64_tr_b16 %0, %1 offset:" OFFSTR : "=v"(dst) : "v"(addr))

#define CAT8(a, b) __builtin_shufflevector(a, b, 0, 1, 2, 3, 4, 5, 6, 7)
#define MFMA_BF16 __builtin_amdgcn_mfma_f32_16x16x32_bf16

#define GLOAD_LDS16(gp, loff)                                                   \
    __builtin_amdgcn_global_load_lds(                                           \
        (const __attribute__((address_space(1))) unsigned int*)(const void*)(gp), \
        (__attribute__((address_space(3))) unsigned int*)(uintptr_t)(loff),     \
        16, 0, 0)

// ---------------------------------------------------------------------------
// Pre-pass: fp32 K/V -> bf16 workspace in LDS-ready layouts.
// One thread = 4 floats of K AND 4 floats of V.  Threads = WS_ELEMS/4.
// ---------------------------------------------------------------------------
#define CVT_THREADS (WS_ELEMS / 4)            // 1,048,576
#define CVT_BLOCKS  (CVT_THREADS / 256)       // 4096

__global__ __launch_bounds__(256)
void cvt_kv(const float* __restrict__ K, const float* __restrict__ V,
            short* __restrict__ wsK, short* __restrict__ wsV)
{
    const int idx = blockIdx.x * 256 + threadIdx.x;   // 0 .. 2^20-1
    if (idx >= (int)CVT_THREADS) return;
    const int g   = idx & 31;          // d-group (4 floats)
    const int kvh = (idx >> 5) & 7;
    const int s   = (idx >> 8) & 2047;
    const int b   = idx >> 19;         // 0..1
    const int d   = g * 4;

    const size_t soff = ((size_t)(b * SEQLEN + s)) * KPITCH + kvh * HDIM + d;
    floatx4 kk = *(const floatx4*)(K + soff);
    floatx4 vv = *(const floatx4*)(V + soff);
    short4v ks, vs;
    #pragma unroll
    for (int j = 0; j < 4; ++j) { ks[j] = bf16bits(kk[j]); vs[j] = bf16bits(vv[j]); }

    // per-(b,kvh): 32 tiles x 8192 elems
    const size_t tbase = (((size_t)(b * H_KV + kvh)) * 32 + (s >> 6)) * 8192;
    // K: rows [key][d] with element XOR swizzle (stays within aligned-4 group)
    *(short4v*)&wsK[tbase + (size_t)(s & 63) * 128 + (d ^ ((s & 7) << 3))] = ks;
    // V: subtiled [d>>4][key][d&15]
    *(short4v*)&wsV[tbase + (size_t)(d >> 4) * 1024 + (s & 63) * 16 + (d & 15)] = vs;
}

// ---------------------------------------------------------------------------
// Main kernel (workspace path).
// ---------------------------------------------------------------------------
__global__ __launch_bounds__(256, 4)
void fa_fwd(const float* __restrict__ Q,
            const short* __restrict__ wsK,
            const short* __restrict__ wsV,
            float* __restrict__ O)
{
    __shared__ __align__(16) short lds_k[64][128];    // 16 KiB, swizzled rows
    __shared__ __align__(16) short lds_v[8][64][16];  // 16 KiB, tr-read subtiles
    __shared__ __align__(16) short lds_pt[4][64][16]; // 8 KiB, per-wave P^T

    int bi = blockIdx.x;
    bi = (bi & 7) * 256 + (bi >> 3);   // XCD-chunked swizzle (2048 = 8*256)
    const int qt  = 31 - (bi & 31);    // long q-tiles first
    const int h   = (bi >> 5) & 31;
    const int b   = bi >> 10;
    const int kvh = h >> 2;
    const int q0  = qt << 6;

    const int tid  = threadIdx.x;
    const int wid  = tid >> 6;
    const int lane = tid & 63;
    const int ln16 = lane & 15;
    const int lg   = lane >> 4;
    const int kxor = (ln16 & 7) << 3;  // element-xor for swizzled K rows

    const float* Qb = Q + (size_t)b * SEQLEN * QPITCH + (size_t)h * HDIM;
    float*       Ob = O + (size_t)b * SEQLEN * QPITCH + (size_t)h * HDIM;
    const char*  wsKh = (const char*)(wsK + ((size_t)(b * H_KV + kvh)) * (SEQLEN * HDIM));
    const char*  wsVh = (const char*)(wsV + ((size_t)(b * H_KV + kvh)) * (SEQLEN * HDIM));

    const uint32_t k_lds = (uint32_t)(uintptr_t)&lds_k[0][0];
    const uint32_t v_lds = (uint32_t)(uintptr_t)&lds_v[0][0][0];
    const uint32_t wave_off = (uint32_t)((tid & 0xC0) * 16);  // wid*1024, wave-uniform

    const uint32_t v_base  = v_lds + (uint32_t)(lg * 256 + ln16 * 8);
    const uint32_t pt_base = (uint32_t)(uintptr_t)&lds_pt[wid][0][0]
                           + (uint32_t)(lg * 256 + ln16 * 8);

    int kvlo = q0 - (WIN - 1);
    if (kvlo < 0) kvlo = 0;
    kvlo &= ~63;

    // async stage: 4 x global_load_lds dwordx4 per wave per tensor per tile
    auto stage_k = [&](int kt) {
        const char* src = wsKh + (size_t)kt * 16384;
        #pragma unroll
        for (int i = 0; i < 4; ++i)
            GLOAD_LDS16(src + i * 4096 + tid * 16, k_lds + i * 4096 + wave_off);
    };
    auto stage_v = [&](int kt) {
        const char* src = wsVh + (size_t)kt * 16384;
        #pragma unroll
        for (int i = 0; i < 4; ++i)
            GLOAD_LDS16(src + i * 4096 + tid * 16, v_lds + i * 4096 + wave_off);
    };

    stage_k(kvlo >> 6);
    stage_v(kvlo >> 6);

    // ---- Q fragments (A operand), registers for the whole kernel.
    short8 qf[4];
    {
        const int qrow = q0 + wid * 16 + ln16;
        const float* qs = Qb + (size_t)qrow * QPITCH + lg * 8;
        #pragma unroll
        for (int kk = 0; kk < 4; ++kk) {
            floatx4 a = *(const floatx4*)(qs + kk * 32);
            floatx4 c = *(const floatx4*)(qs + kk * 32 + 4);
            short8 f;
            #pragma unroll
            for (int j = 0; j < 4; ++j) { f[j] = bf16bits(a[j]); f[4 + j] = bf16bits(c[j]); }
            qf[kk] = f;
        }
    }

    floatx4 oacc[8];
    #pragma unroll
    for (int i = 0; i < 8; ++i) oacc[i] = (floatx4){0.f, 0.f, 0.f, 0.f};
    float m_r[4], l_r[4];
    #pragma unroll
    for (int r = 0; r < 4; ++r) { m_r[r] = NEG_BIG; l_r[r] = 0.f; }

    for (int kk0 = kvlo; kk0 <= q0; kk0 += 64) {
        const bool has_next = (kk0 + 64 <= q0);
        const int  ktn = (kk0 >> 6) + 1;

        // (a) K(t) landed (V(t)'s 4 loads newer) + visible to all waves
        asm volatile("s_waitcnt vmcnt(4)" ::: "memory");
        __builtin_amdgcn_s_barrier();
        __builtin_amdgcn_sched_barrier(0);

        // ---- S = Q K^T (reads swizzled lds_k rows)
        float sc[4][4];
        #pragma unroll
        for (int nt = 0; nt < 4; ++nt) {
            floatx4 acc = (floatx4){0.f, 0.f, 0.f, 0.f};
            #pragma unroll
            for (int kk = 0; kk < 4; ++kk) {
                short8 kf = *(const short8*)&lds_k[nt * 16 + ln16][(kk * 32 + lg * 8) ^ kxor];
                acc = MFMA_BF16(qf[kk], kf, acc, 0, 0, 0);
            }
            #pragma unroll
            for (int r = 0; r < 4; ++r) sc[nt][r] = acc[r];
        }

        // ---- scale + mask
        const bool full = (kk0 + 63 <= q0) && (kk0 >= q0 - 960);
        float pm[4];
        #pragma unroll
        for (int r = 0; r < 4; ++r) pm[r] = NEG_BIG;
        if (full) {
            #pragma unroll
            for (int nt = 0; nt < 4; ++nt)
                #pragma unroll
                for (int r = 0; r < 4; ++r) {
                    sc[nt][r] *= SCALE_LOG2E;
                    pm[r] = fmaxf(pm[r], sc[nt][r]);
                }
        } else {
            #pragma unroll
            for (int nt = 0; nt < 4; ++nt) {
                const int kcol = kk0 + nt * 16 + ln16;
                #pragma unroll
                for (int r = 0; r < 4; ++r) {
                    const int qrow = q0 + wid * 16 + lg * 4 + r;
                    const bool ok = (kcol <= qrow) && (qrow - kcol < WIN);
                    sc[nt][r] = ok ? sc[nt][r] * SCALE_LOG2E : NEG_BIG;
                    pm[r] = fmaxf(pm[r], sc[nt][r]);
                }
            }
        }
        #pragma unroll
        for (int r = 0; r < 4; ++r)
            #pragma unroll
            for (int off = 1; off < 16; off <<= 1)
                pm[r] = fmaxf(pm[r], __shfl_xor(pm[r], off, 16));

        float alpha[4], mne[4];
        #pragma unroll
        for (int r = 0; r < 4; ++r) {
            const float mn = fmaxf(m_r[r], pm[r]);
            const float me = fmaxf(mn, NEG_CLMP);
            alpha[r] = exp2f(m_r[r] - me);
            m_r[r] = mn;
            mne[r] = me;
        }

        // ---- P = exp2(s - m) -> P^T [key][q] (8B quad stores)
        float psum[4] = {0.f, 0.f, 0.f, 0.f};
        #pragma unroll
        for (int nt = 0; nt < 4; ++nt) {
            short4v pq;
            #pragma unroll
            for (int r = 0; r < 4; ++r) {
                const float p = exp2f(sc[nt][r] - mne[r]);
                psum[r] += p;
                pq[r] = bf16bits(p);
            }
            *(short4v*)&lds_pt[wid][nt * 16 + ln16][lg * 4] = pq;
        }
        #pragma unroll
        for (int r = 0; r < 4; ++r) {
            #pragma unroll
            for (int off = 1; off < 16; off <<= 1)
                psum[r] += __shfl_xor(psum[r], off, 16);
            l_r[r] = l_r[r] * alpha[r] + psum[r];
        }
        #pragma unroll
        for (int dt = 0; dt < 8; ++dt)
            #pragma unroll
            for (int r = 0; r < 4; ++r) oacc[dt][r] *= alpha[r];

        // (b) all waves done reading lds_k (and own P writes drained)
        asm volatile("s_waitcnt lgkmcnt(0)" ::: "memory");
        __builtin_amdgcn_s_barrier();
        __builtin_amdgcn_sched_barrier(0);
        if (has_next) stage_k(ktn);           // async into freed lds_k

        // (c) V(t) landed + visible (K(t+1)'s 4 loads stay in flight)
        if (has_next) { asm volatile("s_waitcnt vmcnt(4)" ::: "memory"); }
        else          { asm volatile("s_waitcnt vmcnt(0)" ::: "memory"); }
        __builtin_amdgcn_s_barrier();
        __builtin_amdgcn_sched_barrier(0);

        // ---- O += P V via hardware-transpose reads
        #pragma unroll
        for (int ks = 0; ks < 2; ++ks) {
            const uint32_t pa = pt_base + (uint32_t)(ks * 1024);
            const uint32_t va = v_base  + (uint32_t)(ks * 1024);
            short4v p0, p1, w0a, w0b, w1a, w1b, w2a, w2b, w3a, w3b;
            TR_READ(p0,  pa, "0");     TR_READ(p1,  pa, "128");
            TR_READ(w0a, va, "0");     TR_READ(w0b, va, "128");
            TR_READ(w1a, va, "2048");  TR_READ(w1b, va, "2176");
            TR_READ(w2a, va, "4096");  TR_READ(w2b, va, "4224");
            TR_READ(w3a, va, "6144");  TR_READ(w3b, va, "6272");
            asm volatile("s_waitcnt lgkmcnt(0)" ::: "memory");
            __builtin_amdgcn_sched_barrier(0);
            const short8 pf = CAT8(p0, p1);
            oacc[0] = MFMA_BF16(pf, CAT8(w0a, w0b), oacc[0], 0, 0, 0);
            oacc[1] = MFMA_BF16(pf, CAT8(w1a, w1b), oacc[1], 0, 0, 0);
            oacc[2] = MFMA_BF16(pf, CAT8(w2a, w2b), oacc[2], 0, 0, 0);
            oacc[3] = MFMA_BF16(pf, CAT8(w3a, w3b), oacc[3], 0, 0, 0);
            short4v x0a, x0b, x1a, x1b, x2a, x2b, x3a, x3b;
            TR_READ(x0a, va, "8192");  TR_READ(x0b, va, "8320");
            TR_READ(x1a, va, "10240"); TR_READ(x1b, va, "10368");
            TR_READ(x2a, va, "12288"); TR_READ(x2b, va, "12416");
            TR_READ(x3a, va, "14336"); TR_READ(x3b, va, "14464");
            asm volatile("s_waitcnt lgkmcnt(0)" ::: "memory");
            __builtin_amdgcn_sched_barrier(0);
            oacc[4] = MFMA_BF16(pf, CAT8(x0a, x0b), oacc[4], 0, 0, 0);
            oacc[5] = MFMA_BF16(pf, CAT8(x1a, x1b), oacc[5], 0, 0, 0);
            oacc[6] = MFMA_BF16(pf, CAT8(x2a, x2b), oacc[6], 0, 0, 0);
            oacc[7] = MFMA_BF16(pf, CAT8(x3a, x3b), oacc[7], 0, 0, 0);
        }

        // (d) all waves done reading lds_v
        asm volatile("s_waitcnt lgkmcnt(0)" ::: "memory");
        __builtin_amdgcn_s_barrier();
        __builtin_amdgcn_sched_barrier(0);
        if (has_next) stage_v(ktn);           // async into freed lds_v
    }

    // ---- epilogue
    #pragma unroll
    for (int r = 0; r < 4; ++r) {
        const float inv = 1.0f / l_r[r];
        const int qrow = q0 + wid * 16 + lg * 4 + r;
        float* dst = Ob + (size_t)qrow * QPITCH;
        #pragma unroll
        for (int dt = 0; dt < 8; ++dt)
            dst[dt * 16 + ln16] = oacc[dt][r] * inv;
    }
}

// ---------------------------------------------------------------------------
// Fallback: verified round-2 kernel (used only if ws_size < 16 MiB).
// ---------------------------------------------------------------------------
__global__ __launch_bounds__(256, 2)
void fa_fwd_legacy(const float* __restrict__ Q,
                   const float* __restrict__ K,
                   const float* __restrict__ V,
                   float* __restrict__ O)
{
    __shared__ __align__(16) short lds_k[64][136];
    __shared__ __align__(16) short lds_v[8][64][16];
    __shared__ __align__(16) short lds_pt[4][64][16];

    const int bi  = blockIdx.x;
    const int qt  = bi & 31;
    const int h   = (bi >> 5) & 31;
    const int b   = bi >> 10;
    const int kvh = h >> 2;
    const int q0  = qt << 6;

    const int tid  = threadIdx.x;
    const int wid  = tid >> 6;
    const int lane = tid & 63;
    const int ln16 = lane & 15;
    const int lg   = lane >> 4;

    const float* Qb = Q + (size_t)b * SEQLEN * QPITCH + (size_t)h * HDIM;
    const float* Kb = K + (size_t)b * SEQLEN * KPITCH + (size_t)kvh * HDIM;
    const float* Vb = V + (size_t)b * SEQLEN * KPITCH + (size_t)kvh * HDIM;
    float*       Ob = O + (size_t)b * SEQLEN * QPITCH + (size_t)h * HDIM;

    const uint32_t v_base  = (uint32_t)(uintptr_t)&lds_v[0][0][0]
                           + (uint32_t)(lg * 256 + ln16 * 8);
    const uint32_t pt_base = (uint32_t)(uintptr_t)&lds_pt[wid][0][0]
                           + (uint32_t)(lg * 256 + ln16 * 8);

    int kvlo = q0 - (WIN - 1);
    if (kvlo < 0) kvlo = 0;
    kvlo &= ~63;

    floatx4 pk[8], pv[8];
    auto issue_kv = [&](int kt) {
        #pragma unroll
        for (int i = 0; i < 8; ++i) {
            const int fi  = i * 256 + tid;
            const int key = fi >> 5;
            const int c4  = (fi & 31) * 4;
            const size_t grow = (size_t)(kt + key) * KPITCH + c4;
            pk[i] = *(const floatx4*)(Kb + grow);
            pv[i] = *(const floatx4*)(Vb + grow);
        }
    };
    issue_kv(kvlo);

    short8 qf[4];
    {
        const int qrow = q0 + wid * 16 + ln16;
        const float* qs = Qb + (size_t)qrow * QPITCH + lg * 8;
        #pragma unroll
        for (int kk = 0; kk < 4; ++kk) {
            floatx4 a = *(const floatx4*)(qs + kk * 32);
            floatx4 c = *(const floatx4*)(qs + kk * 32 + 4);
            short8 f;
            #pragma unroll
            for (int j = 0; j < 4; ++j) { f[j] = bf16bits(a[j]); f[4 + j] = bf16bits(c[j]); }
            qf[kk] = f;
        }
    }

    floatx4 oacc[8];
    #pragma unroll
    for (int i = 0; i < 8; ++i) oacc[i] = (floatx4){0.f, 0.f, 0.f, 0.f};
    float m_r[4], l_r[4];
    #pragma unroll
    for (int r = 0; r < 4; ++r) { m_r[r] = NEG_BIG; l_r[r] = 0.f; }

    for (int kk0 = kvlo; kk0 <= q0; kk0 += 64) {
        __syncthreads();
        #pragma unroll
        for (int i = 0; i < 8; ++i) {
            const int fi  = i * 256 + tid;
            const int key = fi >> 5;
            const int c4  = (fi & 31) * 4;
            short4v ksv, vsv;
            #pragma unroll
            for (int j = 0; j < 4; ++j) {
                ksv[j] = bf16bits(pk[i][j]);
                vsv[j] = bf16bits(pv[i][j]);
            }
            *(short4v*)&lds_k[key][c4] = ksv;
            *(short4v*)&lds_v[c4 >> 4][key][c4 & 15] = vsv;
        }
        __syncthreads();
        if (kk0 + 64 <= q0) issue_kv(kk0 + 64);

        float sc[4][4];
        #pragma unroll
        for (int nt = 0; nt < 4; ++nt) {
            floatx4 acc = (floatx4){0.f, 0.f, 0.f, 0.f};
            #pragma unroll
            for (int kk = 0; kk < 4; ++kk) {
                short8 kf = *(const short8*)&lds_k[nt * 16 + ln16][kk * 32 + lg * 8];
                acc = MFMA_BF16(qf[kk], kf, acc, 0, 0, 0);
            }
            #pragma unroll
            for (int r = 0; r < 4; ++r) sc[nt][r] = acc[r];
        }

        const bool full = (kk0 + 63 <= q0) && (kk0 >= q0 - 960);
        float pm[4];
        #pragma unroll
        for (int r = 0; r < 4; ++r) pm[r] = NEG_BIG;
        if (full) {
            #pragma unroll
            for (int nt = 0; nt < 4; ++nt)
                #pragma unroll
                for (int r = 0; r < 4; ++r) {
                    sc[nt][r] *= SCALE_LOG2E;
                    pm[r] = fmaxf(pm[r], sc[nt][r]);
                }
        } else {
            #pragma unroll
            for (int nt = 0; nt < 4; ++nt) {
                const int kcol = kk0 + nt * 16 + ln16;
                #pragma unroll
                for (int r = 0; r < 4; ++r) {
                    const int qrow = q0 + wid * 16 + lg * 4 + r;
                    const bool ok = (kcol <= qrow) && (qrow - kcol < WIN);
                    sc[nt][r] = ok ? sc[nt][r] * SCALE_LOG2E : NEG_BIG;
                    pm[r] = fmaxf(pm[r], sc[nt][r]);
                }
            }
        }
        #pragma unroll
        for (int r = 0; r < 4; ++r)
            #pragma unroll
            for (int off = 1; off < 16; off <<= 1)
                pm[r] = fmaxf(pm[r], __shfl_xor(pm[r], off, 16));

        float alpha[4], mne[4];
        #pragma unroll
        for (int r = 0; r < 4; ++r) {
            const float mn = fmaxf(m_r[r], pm[r]);
            const float me = fmaxf(mn, NEG_CLMP);
            alpha[r] = exp2f(m_r[r] - me);
            m_r[r] = mn;
            mne[r] = me;
        }

        float psum[4] = {0.f, 0.f, 0.f, 0.f};
        #pragma unroll
        for (int nt = 0; nt < 4; ++nt) {
            short4v pq;
            #pragma unroll
            for (int r = 0; r < 4; ++r) {
                const float p = exp2f(sc[nt][r] - mne[r]);
                psum[r] += p;
                pq[r] = bf16bits(p);
            }
            *(short4v*)&lds_pt[wid][nt * 16 + ln16][lg * 4] = pq;
        }
        #pragma unroll
        for (int r = 0; r < 4; ++r) {
            #pragma unroll
            for (int off = 1; off < 16; off <<= 1)
                psum[r] += __shfl_xor(psum[r], off, 16);
            l_r[r] = l_r[r] * alpha[r] + psum[r];
        }
        #pragma unroll
        for (int dt = 0; dt < 8; ++dt)
            #pragma unroll
            for (int r = 0; r < 4; ++r) oacc[dt][r] *= alpha[r];

        asm volatile("s_waitcnt lgkmcnt(0)" ::: "memory");
        __builtin_amdgcn_sched_barrier(0);

        #pragma unroll
        for (int ks = 0; ks < 2; ++ks) {
            const uint32_t pa = pt_base + (uint32_t)(ks * 1024);
            const uint32_t va = v_base  + (uint32_t)(ks * 1024);
            short4v p0, p1, w0a, w0b, w1a, w1b, w2a, w2b, w3a, w3b;
            TR_READ(p0,  pa, "0");     TR_READ(p1,  pa, "128");
            TR_READ(w0a, va, "0");     TR_READ(w0b, va, "128");
            TR_READ(w1a, va, "2048");  TR_READ(w1b, va, "2176");
            TR_READ(w2a, va, "4096");  TR_READ(w2b, va, "4224");
            TR_READ(w3a, va, "6144");  TR_READ(w3b, va, "6272");
            asm volatile("s_waitcnt lgkmcnt(0)" ::: "memory");
            __builtin_amdgcn_sched_barrier(0);
            const short8 pf = CAT8(p0, p1);
            oacc[0] = MFMA_BF16(pf, CAT8(w0a, w0b), oacc[0], 0, 0, 0);
            oacc[1] = MFMA_BF16(pf, CAT8(w1a, w1b), oacc[1], 0, 0, 0);
            oacc[2] = MFMA_BF16(pf, CAT8(w2a, w2b), oacc[2], 0, 0, 0);
            oacc[3] = MFMA_BF16(pf, CAT8(w3a, w3b), oacc[3], 0, 0, 0);
            short4v x0a, x0b, x1a, x1b, x2a, x2b, x3a, x3b;
            TR_READ(x0a, va, "8192");  TR_READ(x0b, va, "8320");
            TR_READ(x1a, va, "10240"); TR_READ(x1b, va, "10368");
            TR_READ(x2a, va, "12288"); TR_READ(x2b, va, "12416");
            TR_READ(x3a, va, "14336"); TR_READ(x3b, va, "14464");
            asm volatile("s_waitcnt lgkmcnt(0)" ::: "memory");
            __builtin_amdgcn_sched_barrier(0);
            oacc[4] = MFMA_BF16(pf, CAT8(x0a, x0b), oacc[4], 0, 0, 0);
            oacc[5] = MFMA_BF16(pf, CAT8(x1a, x1b), oacc[5], 0, 0, 0);
            oacc[6] = MFMA_BF16(pf, CAT8(x2a, x2b), oacc[6], 0, 0, 0);
            oacc[7] = MFMA_BF16(pf, CAT8(x3a, x3b), oacc[7], 0, 0, 0);
        }
    }

    #pragma unroll
    for (int r = 0; r < 4; ++r) {
        const float inv = 1.0f / l_r[r];
        const int qrow = q0 + wid * 16 + lg * 4 + r;
        float* dst = Ob + (size_t)qrow * QPITCH;
        #pragma unroll
        for (int dt = 0; dt < 8; ++dt)
            dst[dt * 16 + ln16] = oacc[dt][r] * inv;
    }
}

extern "C" void kernel_launch(void* const* d_in, const int* in_sizes, int n_in,
                              void* d_out, int out_size, void* d_ws, size_t ws_size,
                              hipStream_t stream) {
    const float* Q = (const float*)d_in[0];
    const float* K = (const float*)d_in[1];
    const float* V = (const float*)d_in[2];
    float* O = (float*)d_out;
    dim3 grid(NBATCH * H_Q * (SEQLEN / 64));   // 2048 blocks

    if (ws_size >= WS_BYTES && d_ws != nullptr) {
        short* wsK = (short*)d_ws;
        short* wsV = wsK + WS_ELEMS;
        cvt_kv<<<dim3((unsigned)CVT_BLOCKS), 256, 0, stream>>>(K, V, wsK, wsV);
        fa_fwd<<<grid, 256, 0, stream>>>(Q, wsK, wsV, O);
    } else {
        fa_fwd_legacy<<<grid, 256, 0, stream>>>(Q, K, V, O);
    }
}